// Round 1
// baseline (5006.346 us; speedup 1.0000x reference)
//
#include <hip/hip_runtime.h>
#include <math.h>

#define NG 8     // groups per block (half-wave per group)
#define NSRC 10  // N
#define DIM 32   // D

__launch_bounds__(256, 4)
__global__ void attn2d_kernel(
    const float* __restrict__ q, const float* __restrict__ k,
    const float* __restrict__ pos, const int* __restrict__ mask,
    const float* __restrict__ Wq, const float* __restrict__ Wk,
    const float* __restrict__ Wv,
    const float* __restrict__ pW1, const float* __restrict__ pb1,
    const float* __restrict__ pW2, const float* __restrict__ pb2,
    const float* __restrict__ aW1, const float* __restrict__ ab1,
    const float* __restrict__ aW2, const float* __restrict__ ab2,
    const float* __restrict__ oW, const float* __restrict__ ob,
    float* __restrict__ out_x, float* __restrict__ out_attn,
    float* __restrict__ out_std, float* __restrict__ out_nks)
{
    // packed (Wq,Wk,Wv,oW)[e*32+d]
    __shared__ float4 Wc[1024];           // 16 KB
    __shared__ float4 kb4[NG * NSRC * 8]; // 10 KB  (k staging; reused for scores)
    __shared__ float4 qb4[NG * 8];        // 1 KB
    __shared__ float4 posb[NG * NSRC];    // 1.25 KB
    __shared__ int    mb[NG * NSRC];
    __shared__ float4 pw1c[4];            // pW1 columns
    __shared__ float  pb1b[4];
    __shared__ float4 pw2t[32];           // pW2 column d as float4 over h
    __shared__ float  pb2b[32];
    __shared__ float4 aw1col[32];         // [c*4+h] : aW1[4c..4c+3][h]  (h in low bits -> distinct banks)
    __shared__ float  ab1b[4];
    __shared__ float4 aw2t[32];           // aW2 column d as float4 over h
    __shared__ float  ab2b[32];
    __shared__ float  obb[32];
    __shared__ float4 ub4[NG * NSRC];     // relu(u)[g][n] over h
    __shared__ float  yb[NG * DIM];       // (vp+pe)*attn summed over n

    const int tid = threadIdx.x;
    const int gb  = tid >> 5;   // group in block
    const int d   = tid & 31;   // channel
    const long long G0 = (long long)blockIdx.x * NG + gb;

    // ---------------- staging ----------------
    {
        const float4* kg4 = (const float4*)k;
        const long long kbase = (long long)blockIdx.x * (NG * NSRC * 8);
        #pragma unroll
        for (int r = 0; r < 3; ++r) {
            int i = tid + r * 256;
            if (i < NG * NSRC * 8) kb4[i] = kg4[kbase + i];
        }
        if (tid < NG * 8)
            qb4[tid] = ((const float4*)q)[(long long)blockIdx.x * NG * 8 + tid];
        if (tid < NG * NSRC) {
            posb[tid] = ((const float4*)pos)[(long long)blockIdx.x * NG * NSRC + tid];
            mb[tid]   = mask[(long long)blockIdx.x * NG * NSRC + tid];
        }
        #pragma unroll
        for (int r = 0; r < 4; ++r) {
            int i = tid + r * 256;  // i = e*32 + dd
            Wc[i] = make_float4(Wq[i], Wk[i], Wv[i], oW[i]);
        }
        if (tid < 4) {
            pw1c[tid] = make_float4(pW1[0*4+tid], pW1[1*4+tid], pW1[2*4+tid], pW1[3*4+tid]);
            pb1b[tid] = pb1[tid];
            ab1b[tid] = ab1[tid];
        }
        if (tid < 32) {
            pw2t[tid] = make_float4(pW2[0*32+tid], pW2[1*32+tid], pW2[2*32+tid], pW2[3*32+tid]);
            pb2b[tid] = pb2[tid];
            aw2t[tid] = make_float4(aW2[0*32+tid], aW2[1*32+tid], aW2[2*32+tid], aW2[3*32+tid]);
            ab2b[tid] = ab2[tid];
            obb[tid]  = ob[tid];
            // aw1col[c*4 + h] = aW1[4c..4c+3][h]
            int h = tid & 3, c = tid >> 2;
            aw1col[tid] = make_float4(aW1[(4*c+0)*4+h], aW1[(4*c+1)*4+h],
                                      aW1[(4*c+2)*4+h], aW1[(4*c+3)*4+h]);
        }
    }
    __syncthreads();

    // ---------------- Phase A: q/k/v projections ----------------
    float qp = 0.f;
    float kp[NSRC], vp[NSRC];
    #pragma unroll
    for (int n = 0; n < NSRC; ++n) { kp[n] = 0.f; vp[n] = 0.f; }

    #pragma unroll
    for (int c = 0; c < 8; ++c) {
        float4 w0 = Wc[(4*c+0)*32 + d];
        float4 w1 = Wc[(4*c+1)*32 + d];
        float4 w2 = Wc[(4*c+2)*32 + d];
        float4 w3 = Wc[(4*c+3)*32 + d];
        float4 q4 = qb4[gb*8 + c];
        qp += q4.x*w0.x + q4.y*w1.x + q4.z*w2.x + q4.w*w3.x;
        #pragma unroll
        for (int n = 0; n < NSRC; ++n) {
            float4 kk = kb4[(gb*NSRC+n)*8 + c];
            kp[n] += kk.x*w0.y + kk.y*w1.y + kk.z*w2.y + kk.w*w3.y;
            vp[n] += kk.x*w0.z + kk.y*w1.z + kk.z*w2.z + kk.w*w3.z;
        }
    }

    // ---------------- Phase B: mask + k statistics (store results NOW) ----------------
    unsigned vbits = 0; int cnt = 0;
    #pragma unroll
    for (int n = 0; n < NSRC; ++n) {
        int m = mb[gb*NSRC + n];
        vbits |= (unsigned)(m != 0) << n;
        cnt += (m != 0);
    }
    if (cnt == 0) { vbits = (1u << NSRC) - 1u; cnt = NSRC; }

    {
        const float cntf = (float)cnt;
        const float rc = 1.f / cntf;
        float mean = 0.f, mabs = 0.f;
        #pragma unroll
        for (int n = 0; n < NSRC; ++n) {
            float w = (float)((vbits >> n) & 1u);
            mean += w * kp[n]; mabs += w * fabsf(kp[n]);
        }
        mean *= rc; mabs *= rc;
        float var = 0.f;
        #pragma unroll
        for (int n = 0; n < NSRC; ++n) {
            float w = (float)((vbits >> n) & 1u);
            float dd = kp[n] - mean; var += w * dd * dd;
        }
        var *= 1.f / fmaxf(cntf - 1.f, 1.f);
        const float stdv = (cnt == 1) ? 0.f : sqrtf(var);
        const float nksv = (cnt == 1) ? 0.f : stdv / (mabs + 1e-6f);
        out_std[G0*DIM + d] = stdv;     // stored early: kills live ranges
        out_nks[G0*DIM + d] = nksv;
    }

    // ---------------- Phase C: positional MLP ----------------
    float pe[NSRC];
    {
        const float4 pw1r0 = pw1c[0], pw1r1 = pw1c[1], pw1r2 = pw1c[2], pw1r3 = pw1c[3];
        const float pb10 = pb1b[0], pb11 = pb1b[1], pb12 = pb1b[2], pb13 = pb1b[3];
        const float4 pw2d = pw2t[d]; const float pb2d = pb2b[d];
        #pragma unroll
        for (int n = 0; n < NSRC; ++n) {
            float4 p4 = posb[gb*NSRC + n];
            float t0 = fmaxf(pb10 + p4.x*pw1r0.x + p4.y*pw1r0.y + p4.z*pw1r0.z + p4.w*pw1r0.w, 0.f);
            float t1 = fmaxf(pb11 + p4.x*pw1r1.x + p4.y*pw1r1.y + p4.z*pw1r1.z + p4.w*pw1r1.w, 0.f);
            float t2 = fmaxf(pb12 + p4.x*pw1r2.x + p4.y*pw1r2.y + p4.z*pw1r2.z + p4.w*pw1r2.w, 0.f);
            float t3 = fmaxf(pb13 + p4.x*pw1r3.x + p4.y*pw1r3.y + p4.z*pw1r3.z + p4.w*pw1r3.w, 0.f);
            pe[n] = pb2d + t0*pw2d.x + t1*pw2d.y + t2*pw2d.z + t3*pw2d.w;
        }
    }

    // ---------------- Phase D: score MLP hidden (cross-lane via LDS) ----------------
    // XOR-swizzle at float4 granularity: chunk' = chunk ^ (n&7).
    // Write (all lanes same n): banks are a permutation -> conflict-free.
    // Read (n = d>>2 varies across lanes): bank base (c^(n&7))*4 distinct per n -> conflict-free.
    // Swizzle stays inside each row's 32-float region, so the same-wave reuse of kb4 is unchanged.
    float* scb = (float*)kb4;  // reuse k staging (same wave -> ordered)
    #pragma unroll
    for (int n = 0; n < NSRC; ++n) {
        int idx = (((d >> 2) ^ (n & 7)) << 2) | (d & 3);
        scb[(gb*NSRC + n)*DIM + idx] = kp[n] - qp + pe[n];
    }

    {
        const float4* scb4 = (const float4*)kb4;
        float* ub = (float*)ub4;
        int n = d >> 2, h = d & 3;
        float u = ab1b[h];
        #pragma unroll
        for (int c = 0; c < 8; ++c) {
            float4 s4 = scb4[(gb*NSRC + n)*8 + (c ^ (n & 7))];
            float4 a4 = aw1col[c*4 + h];
            u += s4.x*a4.x + s4.y*a4.y + s4.z*a4.z + s4.w*a4.w;
        }
        ub[gb*NSRC*4 + n*4 + h] = fmaxf(u, 0.f);
        if (d < 8) {
            int n2 = 8 + (d >> 2);
            float u2 = ab1b[h];
            #pragma unroll
            for (int c = 0; c < 8; ++c) {
                float4 s4 = scb4[(gb*NSRC + n2)*8 + (c ^ (n2 & 7))];
                float4 a4 = aw1col[c*4 + h];
                u2 += s4.x*a4.x + s4.y*a4.y + s4.z*a4.z + s4.w*a4.w;
            }
            ub[gb*NSRC*4 + n2*4 + h] = fmaxf(u2, 0.f);
        }
    }

    // ---------------- Phase E: scores + masked softmax over n ----------------
    float at[NSRC];
    {
        const float4 aw2d = aw2t[d]; const float ab2d = ab2b[d];
        #pragma unroll
        for (int n = 0; n < NSRC; ++n) {
            float4 r4 = ub4[gb*NSRC + n];
            float s = ab2d + r4.x*aw2d.x + r4.y*aw2d.y + r4.z*aw2d.z + r4.w*aw2d.w;
            at[n] = ((vbits >> n) & 1u) ? s : -INFINITY;
        }
    }
    float mx = at[0];
    #pragma unroll
    for (int n = 1; n < NSRC; ++n) mx = fmaxf(mx, at[n]);
    float ssum = 0.f;
    #pragma unroll
    for (int n = 0; n < NSRC; ++n) { float e = __expf(at[n]-mx); at[n] = e; ssum += e; }
    const float rs = 1.f / ssum;

    // ---------------- Phase F: attn store + output projection ----------------
    // Fuse normalize + attn store + y accumulation so at/pe/vp die here.
    float y = 0.f;
    {
        const long long abase = G0*(NSRC*DIM) + d;
        #pragma unroll
        for (int n = 0; n < NSRC; ++n) {
            float a = at[n] * rs;
            y += (vp[n] + pe[n]) * a;
            out_attn[abase + n*DIM] = a;
        }
    }
    yb[gb*DIM + d] = y;
    {
        const float4* yb4 = (const float4*)yb;
        float x = obb[d];
        #pragma unroll
        for (int c = 0; c < 8; ++c) {
            float4 w0 = Wc[(4*c+0)*32 + d];
            float4 w1 = Wc[(4*c+1)*32 + d];
            float4 w2 = Wc[(4*c+2)*32 + d];
            float4 w3 = Wc[(4*c+3)*32 + d];
            float4 y4 = yb4[gb*8 + c];
            x += y4.x*w0.w + y4.y*w1.w + y4.z*w2.w + y4.w*w3.w;
        }
        out_x[G0*DIM + d] = x;
    }
}

extern "C" void kernel_launch(void* const* d_in, const int* in_sizes, int n_in,
                              void* d_out, int out_size, void* d_ws, size_t ws_size,
                              hipStream_t stream) {
    const float* q    = (const float*)d_in[0];
    const float* k    = (const float*)d_in[1];
    const float* pos  = (const float*)d_in[2];
    const int*   mask = (const int*)  d_in[3];
    const float* Wq   = (const float*)d_in[4];
    const float* Wk   = (const float*)d_in[5];
    const float* Wv   = (const float*)d_in[6];
    const float* pW1  = (const float*)d_in[7];
    const float* pb1  = (const float*)d_in[8];
    const float* pW2  = (const float*)d_in[9];
    const float* pb2  = (const float*)d_in[10];
    const float* aW1  = (const float*)d_in[11];
    const float* ab1  = (const float*)d_in[12];
    const float* aW2  = (const float*)d_in[13];
    const float* ab2  = (const float*)d_in[14];
    const float* oW   = (const float*)d_in[15];
    const float* ob   = (const float*)d_in[16];

    const int G = in_sizes[0] / DIM;          // R*S = 131072 groups
    const int blocks = G / NG;                // 16384

    float* out_x    = (float*)d_out;
    float* out_attn = out_x + (long long)G * DIM;
    float* out_std  = out_attn + (long long)G * NSRC * DIM;
    float* out_nks  = out_std + (long long)G * DIM;

    attn2d_kernel<<<blocks, 256, 0, stream>>>(
        q, k, pos, mask, Wq, Wk, Wv, pW1, pb1, pW2, pb2,
        aW1, ab1, aW2, ab2, oW, ob,
        out_x, out_attn, out_std, out_nks);
}

// Round 2
// 1935.803 us; speedup vs baseline: 2.5862x; 2.5862x over previous
//
#include <hip/hip_runtime.h>
#include <math.h>

#define NG 8     // groups per block (half-wave per group)
#define NSRC 10  // N
#define DIM 32   // D

// NOTE on launch bounds: empirically on this toolchain (256,4) produced
// VGPR_Count=64 (catastrophic spills, 17.9 GB scratch traffic), i.e. the
// cap behaves like 512/(2*arg), NOT the documented 512/arg. (256,2) is
// the calibrated choice for a 128-reg cap -> 4 waves/SIMD, matching the
// 4 blocks/CU that 33.8 KB LDS allows.
__launch_bounds__(256, 2)
__global__ void attn2d_kernel(
    const float* __restrict__ q, const float* __restrict__ k,
    const float* __restrict__ pos, const int* __restrict__ mask,
    const float* __restrict__ Wq, const float* __restrict__ Wk,
    const float* __restrict__ Wv,
    const float* __restrict__ pW1, const float* __restrict__ pb1,
    const float* __restrict__ pW2, const float* __restrict__ pb2,
    const float* __restrict__ aW1, const float* __restrict__ ab1,
    const float* __restrict__ aW2, const float* __restrict__ ab2,
    const float* __restrict__ oW, const float* __restrict__ ob,
    float* __restrict__ out_x, float* __restrict__ out_attn,
    float* __restrict__ out_std, float* __restrict__ out_nks)
{
    // packed (Wq,Wk,Wv,oW)[e*32+d]
    __shared__ float4 Wc[1024];           // 16 KB
    __shared__ float4 kb4[NG * NSRC * 8]; // 10 KB  (k staging; reused for scores, then vpe)
    __shared__ float4 qb4[NG * 8];        // 1 KB
    __shared__ float4 posb[NG * NSRC];    // 1.25 KB
    __shared__ int    mb[NG * NSRC];
    __shared__ float4 pw1c[4];            // pW1 columns
    __shared__ float  pb1b[4];
    __shared__ float4 pw2t[32];           // pW2 column d as float4 over h
    __shared__ float  pb2b[32];
    __shared__ float4 aw1col[32];         // [c*4+h] : aW1[4c..4c+3][h]
    __shared__ float  ab1b[4];
    __shared__ float4 aw2t[32];           // aW2 column d as float4 over h
    __shared__ float  ab2b[32];
    __shared__ float  obb[32];
    __shared__ float4 ub4[NG * NSRC];     // relu(u)[g][n] over h
    __shared__ float  yb[NG * DIM];       // (vp+pe)*attn summed over n

    const int tid = threadIdx.x;
    const int gb  = tid >> 5;   // group in block
    const int d   = tid & 31;   // channel
    const long long G0 = (long long)blockIdx.x * NG + gb;

    // ---------------- staging ----------------
    {
        const float4* kg4 = (const float4*)k;
        const long long kbase = (long long)blockIdx.x * (NG * NSRC * 8);
        #pragma unroll
        for (int r = 0; r < 3; ++r) {
            int i = tid + r * 256;
            if (i < NG * NSRC * 8) kb4[i] = kg4[kbase + i];
        }
        if (tid < NG * 8)
            qb4[tid] = ((const float4*)q)[(long long)blockIdx.x * NG * 8 + tid];
        if (tid < NG * NSRC) {
            posb[tid] = ((const float4*)pos)[(long long)blockIdx.x * NG * NSRC + tid];
            mb[tid]   = mask[(long long)blockIdx.x * NG * NSRC + tid];
        }
        #pragma unroll
        for (int r = 0; r < 4; ++r) {
            int i = tid + r * 256;  // i = e*32 + dd
            Wc[i] = make_float4(Wq[i], Wk[i], Wv[i], oW[i]);
        }
        if (tid < 4) {
            pw1c[tid] = make_float4(pW1[0*4+tid], pW1[1*4+tid], pW1[2*4+tid], pW1[3*4+tid]);
            pb1b[tid] = pb1[tid];
            ab1b[tid] = ab1[tid];
        }
        if (tid < 32) {
            pw2t[tid] = make_float4(pW2[0*32+tid], pW2[1*32+tid], pW2[2*32+tid], pW2[3*32+tid]);
            pb2b[tid] = pb2[tid];
            aw2t[tid] = make_float4(aW2[0*32+tid], aW2[1*32+tid], aW2[2*32+tid], aW2[3*32+tid]);
            ab2b[tid] = ab2[tid];
            obb[tid]  = ob[tid];
            // aw1col[c*4 + h] = aW1[4c..4c+3][h]
            int h = tid & 3, c = tid >> 2;
            aw1col[tid] = make_float4(aW1[(4*c+0)*4+h], aW1[(4*c+1)*4+h],
                                      aW1[(4*c+2)*4+h], aW1[(4*c+3)*4+h]);
        }
    }
    __syncthreads();

    // ---------------- Phase A: q/k/v projections ----------------
    float qp = 0.f;
    float kp[NSRC], vp[NSRC];
    #pragma unroll
    for (int n = 0; n < NSRC; ++n) { kp[n] = 0.f; vp[n] = 0.f; }

    #pragma unroll
    for (int c = 0; c < 8; ++c) {
        float4 w0 = Wc[(4*c+0)*32 + d];
        float4 w1 = Wc[(4*c+1)*32 + d];
        float4 w2 = Wc[(4*c+2)*32 + d];
        float4 w3 = Wc[(4*c+3)*32 + d];
        float4 q4 = qb4[gb*8 + c];
        qp += q4.x*w0.x + q4.y*w1.x + q4.z*w2.x + q4.w*w3.x;
        #pragma unroll
        for (int n = 0; n < NSRC; ++n) {
            float4 kk = kb4[(gb*NSRC+n)*8 + c];
            kp[n] += kk.x*w0.y + kk.y*w1.y + kk.z*w2.y + kk.w*w3.y;
            vp[n] += kk.x*w0.z + kk.y*w1.z + kk.z*w2.z + kk.w*w3.z;
        }
    }

    // ---------------- Phase B: mask + k statistics (store results NOW) ----------------
    unsigned vbits = 0; int cnt = 0;
    #pragma unroll
    for (int n = 0; n < NSRC; ++n) {
        int m = mb[gb*NSRC + n];
        vbits |= (unsigned)(m != 0) << n;
        cnt += (m != 0);
    }
    if (cnt == 0) { vbits = (1u << NSRC) - 1u; cnt = NSRC; }

    {
        const float cntf = (float)cnt;
        const float rc = 1.f / cntf;
        float mean = 0.f, mabs = 0.f;
        #pragma unroll
        for (int n = 0; n < NSRC; ++n) {
            float w = (float)((vbits >> n) & 1u);
            mean += w * kp[n]; mabs += w * fabsf(kp[n]);
        }
        mean *= rc; mabs *= rc;
        float var = 0.f;
        #pragma unroll
        for (int n = 0; n < NSRC; ++n) {
            float w = (float)((vbits >> n) & 1u);
            float dd = kp[n] - mean; var += w * dd * dd;
        }
        var *= 1.f / fmaxf(cntf - 1.f, 1.f);
        const float stdv = (cnt == 1) ? 0.f : sqrtf(var);
        const float nksv = (cnt == 1) ? 0.f : stdv / (mabs + 1e-6f);
        out_std[G0*DIM + d] = stdv;     // stored early: kills live ranges
        out_nks[G0*DIM + d] = nksv;
    }

    // ---------------- Phase C: positional MLP ----------------
    float pe[NSRC];
    {
        const float4 pw1r0 = pw1c[0], pw1r1 = pw1c[1], pw1r2 = pw1c[2], pw1r3 = pw1c[3];
        const float pb10 = pb1b[0], pb11 = pb1b[1], pb12 = pb1b[2], pb13 = pb1b[3];
        const float4 pw2d = pw2t[d]; const float pb2d = pb2b[d];
        #pragma unroll
        for (int n = 0; n < NSRC; ++n) {
            float4 p4 = posb[gb*NSRC + n];
            float t0 = fmaxf(pb10 + p4.x*pw1r0.x + p4.y*pw1r0.y + p4.z*pw1r0.z + p4.w*pw1r0.w, 0.f);
            float t1 = fmaxf(pb11 + p4.x*pw1r1.x + p4.y*pw1r1.y + p4.z*pw1r1.z + p4.w*pw1r1.w, 0.f);
            float t2 = fmaxf(pb12 + p4.x*pw1r2.x + p4.y*pw1r2.y + p4.z*pw1r2.z + p4.w*pw1r2.w, 0.f);
            float t3 = fmaxf(pb13 + p4.x*pw1r3.x + p4.y*pw1r3.y + p4.z*pw1r3.z + p4.w*pw1r3.w, 0.f);
            pe[n] = pb2d + t0*pw2d.x + t1*pw2d.y + t2*pw2d.z + t3*pw2d.w;
        }
    }

    // ---------------- Phase D1: score MLP hidden (cross-lane via LDS) ----------------
    // XOR-swizzle at float4 granularity: chunk' = chunk ^ (n&7).  kb4 reuse is
    // same-wave -> LDS pipe is in-order per wave, no barrier needed.
    float* scb = (float*)kb4;
    #pragma unroll
    for (int n = 0; n < NSRC; ++n) {
        int idx = (((d >> 2) ^ (n & 7)) << 2) | (d & 3);
        scb[(gb*NSRC + n)*DIM + idx] = kp[n] - qp + pe[n];
    }

    {
        const float4* scb4 = (const float4*)kb4;
        float* ub = (float*)ub4;
        int n = d >> 2, h = d & 3;
        float u = ab1b[h];
        #pragma unroll
        for (int c = 0; c < 8; ++c) {
            float4 s4 = scb4[(gb*NSRC + n)*8 + (c ^ (n & 7))];
            float4 a4 = aw1col[c*4 + h];
            u += s4.x*a4.x + s4.y*a4.y + s4.z*a4.z + s4.w*a4.w;
        }
        ub[gb*NSRC*4 + n*4 + h] = fmaxf(u, 0.f);
        if (d < 8) {
            int n2 = 8 + (d >> 2);
            float u2 = ab1b[h];
            #pragma unroll
            for (int c = 0; c < 8; ++c) {
                float4 s4 = scb4[(gb*NSRC + n2)*8 + (c ^ (n2 & 7))];
                float4 a4 = aw1col[c*4 + h];
                u2 += s4.x*a4.x + s4.y*a4.y + s4.z*a4.z + s4.w*a4.w;
            }
            ub[gb*NSRC*4 + n2*4 + h] = fmaxf(u2, 0.f);
        }
    }

    // ---------------- Phase D2: offload vp+pe to LDS (kills 20 long-range VGPRs) ----
    // Score region of kb4 is dead after the reads above; same-wave in-order LDS
    // guarantees the reads saw the scores. Anti-dependence on kb4 keeps the
    // compiler from hoisting these writes above the reads.
    {
        float* vpeb = (float*)kb4;
        #pragma unroll
        for (int n = 0; n < NSRC; ++n)
            vpeb[(gb*NSRC + n)*DIM + d] = vp[n] + pe[n];
    }

    // ---------------- Phase E: scores + masked softmax over n ----------------
    float at[NSRC];
    {
        const float4 aw2d = aw2t[d]; const float ab2d = ab2b[d];
        #pragma unroll
        for (int n = 0; n < NSRC; ++n) {
            float4 r4 = ub4[gb*NSRC + n];
            float s = ab2d + r4.x*aw2d.x + r4.y*aw2d.y + r4.z*aw2d.z + r4.w*aw2d.w;
            at[n] = ((vbits >> n) & 1u) ? s : -INFINITY;
        }
    }
    float mx = at[0];
    #pragma unroll
    for (int n = 1; n < NSRC; ++n) mx = fmaxf(mx, at[n]);
    float ssum = 0.f;
    #pragma unroll
    for (int n = 0; n < NSRC; ++n) { float e = __expf(at[n]-mx); at[n] = e; ssum += e; }
    const float rs = 1.f / ssum;

    // ---------------- Phase F: attn store + output projection ----------------
    float y = 0.f;
    {
        const float* vpeb = (const float*)kb4;
        const long long abase = G0*(NSRC*DIM) + d;
        #pragma unroll
        for (int n = 0; n < NSRC; ++n) {
            float a = at[n] * rs;
            y += vpeb[(gb*NSRC + n)*DIM + d] * a;
            out_attn[abase + n*DIM] = a;
        }
    }
    yb[gb*DIM + d] = y;
    {
        const float4* yb4 = (const float4*)yb;
        float x = obb[d];
        #pragma unroll
        for (int c = 0; c < 8; ++c) {
            float4 w0 = Wc[(4*c+0)*32 + d];
            float4 w1 = Wc[(4*c+1)*32 + d];
            float4 w2 = Wc[(4*c+2)*32 + d];
            float4 w3 = Wc[(4*c+3)*32 + d];
            float4 y4 = yb4[gb*8 + c];
            x += y4.x*w0.w + y4.y*w1.w + y4.z*w2.w + y4.w*w3.w;
        }
        out_x[G0*DIM + d] = x;
    }
}

extern "C" void kernel_launch(void* const* d_in, const int* in_sizes, int n_in,
                              void* d_out, int out_size, void* d_ws, size_t ws_size,
                              hipStream_t stream) {
    const float* q    = (const float*)d_in[0];
    const float* k    = (const float*)d_in[1];
    const float* pos  = (const float*)d_in[2];
    const int*   mask = (const int*)  d_in[3];
    const float* Wq   = (const float*)d_in[4];
    const float* Wk   = (const float*)d_in[5];
    const float* Wv   = (const float*)d_in[6];
    const float* pW1  = (const float*)d_in[7];
    const float* pb1  = (const float*)d_in[8];
    const float* pW2  = (const float*)d_in[9];
    const float* pb2  = (const float*)d_in[10];
    const float* aW1  = (const float*)d_in[11];
    const float* ab1  = (const float*)d_in[12];
    const float* aW2  = (const float*)d_in[13];
    const float* ab2  = (const float*)d_in[14];
    const float* oW   = (const float*)d_in[15];
    const float* ob   = (const float*)d_in[16];

    const int G = in_sizes[0] / DIM;          // R*S = 131072 groups
    const int blocks = G / NG;                // 16384

    float* out_x    = (float*)d_out;
    float* out_attn = out_x + (long long)G * DIM;
    float* out_std  = out_attn + (long long)G * NSRC * DIM;
    float* out_nks  = out_std + (long long)G * DIM;

    attn2d_kernel<<<blocks, 256, 0, stream>>>(
        q, k, pos, mask, Wq, Wk, Wv, pW1, pb1, pW2, pb2,
        aW1, ab1, aW2, ab2, oW, ob,
        out_x, out_attn, out_std, out_nks);
}

// Round 4
// 574.606 us; speedup vs baseline: 8.7127x; 3.3689x over previous
//
#include <hip/hip_runtime.h>
#include <math.h>

#define NG 8     // groups per block (half-wave per group)
#define NSRC 10  // N
#define DIM 32   // D

// launch_bounds calibration on this toolchain: (256,4) -> VGPR cap 64,
// (256,2) -> cap 128, none -> 256.  Cap 128 + 33.6 KB LDS = 4 blocks/CU
// = 16 waves/CU.  Structure keeps true demand ~70-85 regs -> spill-free.
__launch_bounds__(256, 2)
__global__ void attn2d_kernel(
    const float* __restrict__ q, const float* __restrict__ k,
    const float* __restrict__ pos, const int* __restrict__ mask,
    const float* __restrict__ Wq, const float* __restrict__ Wk,
    const float* __restrict__ Wv,
    const float* __restrict__ pW1, const float* __restrict__ pb1,
    const float* __restrict__ pW2, const float* __restrict__ pb2,
    const float* __restrict__ aW1, const float* __restrict__ ab1,
    const float* __restrict__ aW2, const float* __restrict__ ab2,
    const float* __restrict__ oW, const float* __restrict__ ob,
    float* __restrict__ out_x, float* __restrict__ out_attn,
    float* __restrict__ out_std, float* __restrict__ out_nks)
{
    // Separately-declared arrays: compiler-managed layout (round-3 lesson:
    // hand-packed offsets under-sized yb -> OOB writes -> wrong out_x).
    __shared__ float4 Wq4[256];           // Wq4[c*32+d] = Wq[4c..4c+3][d]
    __shared__ float4 Wk4[256];
    __shared__ float4 Wv4[256];
    __shared__ float4 Wo4[256];           // 16 KB total weights
    __shared__ float4 kb4[NG * NSRC * 8]; // 10 KB  k staging; reused for scores
    __shared__ float4 qb4[NG * 8];        // 1 KB
    __shared__ float4 posb[NG * NSRC];    // 1.25 KB
    __shared__ float4 ub4[NG * NSRC];     // relu(u)[g][n] over h
    __shared__ float4 pw1c[4];
    __shared__ float4 pw2t[32];
    __shared__ float4 aw1col[32];         // [c*4+h] : aW1[4c..4c+3][h]
    __shared__ float4 aw2t[32];
    __shared__ int    mb[NG * NSRC];
    __shared__ float  pb1b[4];
    __shared__ float  ab1b[4];
    __shared__ float  pb2b[32];
    __shared__ float  ab2b[32];
    __shared__ float  obb[32];
    __shared__ float  yb[NG * DIM];       // 256 floats (FULL size — round-3 bug)

    const int tid = threadIdx.x;
    const int gb  = tid >> 5;   // group in block / weight c-chunk during staging
    const int d   = tid & 31;   // channel
    const long long G0 = (long long)blockIdx.x * NG + gb;

    // ---------------- staging ----------------
    {
        // weights: thread (cc,dd) packs 4 consecutive input dims of column dd
        const int cc = gb, dd = d;
        Wq4[tid] = make_float4(Wq[(4*cc+0)*32+dd], Wq[(4*cc+1)*32+dd],
                               Wq[(4*cc+2)*32+dd], Wq[(4*cc+3)*32+dd]);
        Wk4[tid] = make_float4(Wk[(4*cc+0)*32+dd], Wk[(4*cc+1)*32+dd],
                               Wk[(4*cc+2)*32+dd], Wk[(4*cc+3)*32+dd]);
        Wv4[tid] = make_float4(Wv[(4*cc+0)*32+dd], Wv[(4*cc+1)*32+dd],
                               Wv[(4*cc+2)*32+dd], Wv[(4*cc+3)*32+dd]);
        Wo4[tid] = make_float4(oW[(4*cc+0)*32+dd], oW[(4*cc+1)*32+dd],
                               oW[(4*cc+2)*32+dd], oW[(4*cc+3)*32+dd]);

        const float4* kg4 = (const float4*)k;
        const long long kbase = (long long)blockIdx.x * (NG * NSRC * 8);
        #pragma unroll
        for (int r = 0; r < 3; ++r) {
            int i = tid + r * 256;
            if (i < NG * NSRC * 8) kb4[i] = kg4[kbase + i];
        }
        if (tid < NG * 8)
            qb4[tid] = ((const float4*)q)[(long long)blockIdx.x * NG * 8 + tid];
        if (tid < NG * NSRC) {
            posb[tid] = ((const float4*)pos)[(long long)blockIdx.x * NG * NSRC + tid];
            mb[tid]   = mask[(long long)blockIdx.x * NG * NSRC + tid];
        }
        if (tid < 4) {
            pw1c[tid] = make_float4(pW1[0*4+tid], pW1[1*4+tid], pW1[2*4+tid], pW1[3*4+tid]);
            pb1b[tid] = pb1[tid];
            ab1b[tid] = ab1[tid];
        }
        if (tid < 32) {
            pw2t[tid] = make_float4(pW2[0*32+tid], pW2[1*32+tid], pW2[2*32+tid], pW2[3*32+tid]);
            pb2b[tid] = pb2[tid];
            aw2t[tid] = make_float4(aW2[0*32+tid], aW2[1*32+tid], aW2[2*32+tid], aW2[3*32+tid]);
            ab2b[tid] = ab2[tid];
            obb[tid]  = ob[tid];
            // aw1col[c*4 + h] = aW1[4c..4c+3][h]
            int h = tid & 3, c = tid >> 2;
            aw1col[tid] = make_float4(aW1[(4*c+0)*4+h], aW1[(4*c+1)*4+h],
                                      aW1[(4*c+2)*4+h], aW1[(4*c+3)*4+h]);
        }
    }
    __syncthreads();

    // ---------------- positional MLP first (pe folds into vp below) ----------------
    float pe[NSRC];
    {
        const float4 pw1r0 = pw1c[0], pw1r1 = pw1c[1], pw1r2 = pw1c[2], pw1r3 = pw1c[3];
        const float pb10 = pb1b[0], pb11 = pb1b[1], pb12 = pb1b[2], pb13 = pb1b[3];
        const float4 pw2d = pw2t[d]; const float pb2d = pb2b[d];
        #pragma unroll
        for (int n = 0; n < NSRC; ++n) {
            float4 p4 = posb[gb*NSRC + n];
            float t0 = fmaxf(pb10 + p4.x*pw1r0.x + p4.y*pw1r0.y + p4.z*pw1r0.z + p4.w*pw1r0.w, 0.f);
            float t1 = fmaxf(pb11 + p4.x*pw1r1.x + p4.y*pw1r1.y + p4.z*pw1r1.z + p4.w*pw1r1.w, 0.f);
            float t2 = fmaxf(pb12 + p4.x*pw1r2.x + p4.y*pw1r2.y + p4.z*pw1r2.z + p4.w*pw1r2.w, 0.f);
            float t3 = fmaxf(pb13 + p4.x*pw1r3.x + p4.y*pw1r3.y + p4.z*pw1r3.z + p4.w*pw1r3.w, 0.f);
            pe[n] = pb2d + t0*pw2d.x + t1*pw2d.y + t2*pw2d.z + t3*pw2d.w;
        }
    }

    // ---------------- mask bits ----------------
    unsigned vbits = 0; int cnt = 0;
    #pragma unroll
    for (int n = 0; n < NSRC; ++n) {
        int m = mb[gb*NSRC + n];
        vbits |= (unsigned)(m != 0) << n;
        cnt += (m != 0);
    }
    if (cnt == 0) { vbits = (1u << NSRC) - 1u; cnt = NSRC; }

    // ---------------- Phase A: q/k/v projections ----------------
    float qp = 0.f;
    float kp[NSRC], vp[NSRC];
    #pragma unroll
    for (int n = 0; n < NSRC; ++n) { kp[n] = 0.f; vp[n] = 0.f; }

    // unroll 2 (not 8): bounds in-flight LDS loads so the 128-reg cap
    // doesn't trigger spills (round-2 lesson: full unroll spilled 6.3 GB).
    #pragma unroll 2
    for (int c = 0; c < 8; ++c) {
        float4 wq = Wq4[c*32 + d];
        float4 wk = Wk4[c*32 + d];
        float4 wv = Wv4[c*32 + d];
        float4 q4 = qb4[gb*8 + c];
        qp += q4.x*wq.x + q4.y*wq.y + q4.z*wq.z + q4.w*wq.w;
        #pragma unroll
        for (int n = 0; n < NSRC; ++n) {
            float4 kk = kb4[(gb*NSRC+n)*8 + c];
            kp[n] += kk.x*wk.x + kk.y*wk.y + kk.z*wk.z + kk.w*wk.w;
            vp[n] += kk.x*wv.x + kk.y*wv.y + kk.z*wv.z + kk.w*wv.w;
        }
    }

    // ---------------- k statistics (store results NOW) ----------------
    {
        const float cntf = (float)cnt;
        const float rc = 1.f / cntf;
        float mean = 0.f, mabs = 0.f;
        #pragma unroll
        for (int n = 0; n < NSRC; ++n) {
            float w = (float)((vbits >> n) & 1u);
            mean += w * kp[n]; mabs += w * fabsf(kp[n]);
        }
        mean *= rc; mabs *= rc;
        float var = 0.f;
        #pragma unroll
        for (int n = 0; n < NSRC; ++n) {
            float w = (float)((vbits >> n) & 1u);
            float dd2 = kp[n] - mean; var += w * dd2 * dd2;
        }
        var *= 1.f / fmaxf(cntf - 1.f, 1.f);
        const float stdv = (cnt == 1) ? 0.f : sqrtf(var);
        const float nksv = (cnt == 1) ? 0.f : stdv / (mabs + 1e-6f);
        out_std[G0*DIM + d] = stdv;
        out_nks[G0*DIM + d] = nksv;
    }

    // fold pe into vp: vp becomes (vp+pe); pe still live only through score write
    #pragma unroll
    for (int n = 0; n < NSRC; ++n) vp[n] += pe[n];

    // ---------------- scores -> LDS (swizzled); kp/qp/pe die here ----------------
    // XOR-swizzle at float4 granularity: chunk' = chunk ^ (n&7). kb4 reuse is
    // same-wave (each group's score region == its own k region) -> in-order, safe.
    float* scb = (float*)kb4;
    #pragma unroll
    for (int n = 0; n < NSRC; ++n) {
        int idx = (((d >> 2) ^ (n & 7)) << 2) | (d & 3);
        scb[(gb*NSRC + n)*DIM + idx] = kp[n] - qp + pe[n];
    }

    // ---------------- score MLP hidden (cross-lane via LDS) ----------------
    {
        const float4* scb4 = (const float4*)kb4;
        float* ub = (float*)ub4;
        int n = d >> 2, h = d & 3;
        float u = ab1b[h];
        #pragma unroll
        for (int c = 0; c < 8; ++c) {
            float4 s4 = scb4[(gb*NSRC + n)*8 + (c ^ (n & 7))];
            float4 a4 = aw1col[c*4 + h];
            u += s4.x*a4.x + s4.y*a4.y + s4.z*a4.z + s4.w*a4.w;
        }
        ub[gb*NSRC*4 + n*4 + h] = fmaxf(u, 0.f);
        if (d < 8) {
            int n2 = 8 + (d >> 2);
            float u2 = ab1b[h];
            #pragma unroll
            for (int c = 0; c < 8; ++c) {
                float4 s4 = scb4[(gb*NSRC + n2)*8 + (c ^ (n2 & 7))];
                float4 a4 = aw1col[c*4 + h];
                u2 += s4.x*a4.x + s4.y*a4.y + s4.z*a4.z + s4.w*a4.w;
            }
            ub[gb*NSRC*4 + n2*4 + h] = fmaxf(u2, 0.f);
        }
    }

    // ---------------- scores + masked softmax over n ----------------
    float at[NSRC];
    {
        const float4 aw2d = aw2t[d]; const float ab2d = ab2b[d];
        #pragma unroll
        for (int n = 0; n < NSRC; ++n) {
            float4 r4 = ub4[gb*NSRC + n];
            float s = ab2d + r4.x*aw2d.x + r4.y*aw2d.y + r4.z*aw2d.z + r4.w*aw2d.w;
            at[n] = ((vbits >> n) & 1u) ? s : -INFINITY;
        }
    }
    float mx = at[0];
    #pragma unroll
    for (int n = 1; n < NSRC; ++n) mx = fmaxf(mx, at[n]);
    float ssum = 0.f;
    #pragma unroll
    for (int n = 0; n < NSRC; ++n) { float e = __expf(at[n]-mx); at[n] = e; ssum += e; }
    const float rs = 1.f / ssum;

    // ---------------- attn store + output projection ----------------
    float y = 0.f;
    {
        const long long abase = G0*(NSRC*DIM) + d;
        #pragma unroll
        for (int n = 0; n < NSRC; ++n) {
            float a = at[n] * rs;
            y += vp[n] * a;          // vp == vp+pe
            out_attn[abase + n*DIM] = a;
        }
    }
    yb[gb*DIM + d] = y;
    {
        const float4* yb4 = (const float4*)yb;
        float x = obb[d];
        #pragma unroll
        for (int c = 0; c < 8; ++c) {
            float4 wo = Wo4[c*32 + d];
            float4 y4 = yb4[gb*8 + c];
            x += y4.x*wo.x + y4.y*wo.y + y4.z*wo.z + y4.w*wo.w;
        }
        out_x[G0*DIM + d] = x;
    }
}

extern "C" void kernel_launch(void* const* d_in, const int* in_sizes, int n_in,
                              void* d_out, int out_size, void* d_ws, size_t ws_size,
                              hipStream_t stream) {
    const float* q    = (const float*)d_in[0];
    const float* k    = (const float*)d_in[1];
    const float* pos  = (const float*)d_in[2];
    const int*   mask = (const int*)  d_in[3];
    const float* Wq   = (const float*)d_in[4];
    const float* Wk   = (const float*)d_in[5];
    const float* Wv   = (const float*)d_in[6];
    const float* pW1  = (const float*)d_in[7];
    const float* pb1  = (const float*)d_in[8];
    const float* pW2  = (const float*)d_in[9];
    const float* pb2  = (const float*)d_in[10];
    const float* aW1  = (const float*)d_in[11];
    const float* ab1  = (const float*)d_in[12];
    const float* aW2  = (const float*)d_in[13];
    const float* ab2  = (const float*)d_in[14];
    const float* oW   = (const float*)d_in[15];
    const float* ob   = (const float*)d_in[16];

    const int G = in_sizes[0] / DIM;          // R*S = 131072 groups
    const int blocks = G / NG;                // 16384

    float* out_x    = (float*)d_out;
    float* out_attn = out_x + (long long)G * DIM;
    float* out_std  = out_attn + (long long)G * NSRC * DIM;
    float* out_nks  = out_std + (long long)G * DIM;

    attn2d_kernel<<<blocks, 256, 0, stream>>>(
        q, k, pos, mask, Wq, Wk, Wv, pW1, pb1, pW2, pb2,
        aW1, ab1, aW2, ab2, oW, ob,
        out_x, out_attn, out_std, out_nks);
}

// Round 5
// 524.849 us; speedup vs baseline: 9.5386x; 1.0948x over previous
//
#include <hip/hip_runtime.h>
#include <math.h>

#define NG 8     // groups per block (half-wave per group)
#define NSRC 10  // N
#define DIM 32   // D
#define TILES 4  // tiles per persistent block (weights staged once)

typedef float floatx2 __attribute__((ext_vector_type(2)));

// launch_bounds calibration on this toolchain: (256,4) -> VGPR cap 64 (spills!),
// (256,2) -> cap 128 (spill-free at ~120 demand). Keep (256,2).
__launch_bounds__(256, 2)
__global__ void attn2d_kernel(
    const float* __restrict__ q, const float* __restrict__ k,
    const float* __restrict__ pos, const int* __restrict__ mask,
    const float* __restrict__ Wq, const float* __restrict__ Wk,
    const float* __restrict__ Wv,
    const float* __restrict__ pW1, const float* __restrict__ pb1,
    const float* __restrict__ pW2, const float* __restrict__ pb2,
    const float* __restrict__ aW1, const float* __restrict__ ab1,
    const float* __restrict__ aW2, const float* __restrict__ ab2,
    const float* __restrict__ oW, const float* __restrict__ ob,
    float* __restrict__ out_x, float* __restrict__ out_attn,
    float* __restrict__ out_std, float* __restrict__ out_nks)
{
    // Separately-declared arrays (round-3 lesson: no hand-packed offsets).
    __shared__ float4 Wq4[256];            // Wq4[c*32+d]  = Wq[4c..4c+3][d]
    __shared__ float4 Wkv4[512];           // [(2c+p)*32+d] = (Wk[4c+2p][d],Wv[4c+2p][d],Wk[4c+2p+1][d],Wv[4c+2p+1][d])
    __shared__ float4 Wo4[256];            // 16 KB weights total
    __shared__ float4 kb4[NG * NSRC * 8];  // 10 KB k staging; reused for swizzled scores
    __shared__ float4 qb4[NG * 8];         // 1 KB
    __shared__ float4 posb[NG * NSRC];     // holds RELU'D POS-HIDDEN (computed in staging)
    __shared__ float4 ub4[NG * NSRC];      // relu(u)[g][n] over h; later hosts y (gb-local)
    __shared__ float4 pw2t[32];
    __shared__ float4 aw1col[32];          // [c*4+h] : aW1[4c..4c+3][h]
    __shared__ float4 aw2t[32];
    __shared__ int    mb[NG * NSRC];
    __shared__ float  ab1b[4];
    __shared__ float  pb2b[32];
    __shared__ float  ab2b[32];
    __shared__ float  obb[32];
    // total ~32.4 KB

    const int tid = threadIdx.x;
    const int gb  = tid >> 5;
    const int d   = tid & 31;

    // ---------------- tile-invariant staging (once per block) ----------------
    {
        const int cc = gb, dd = d;
        Wq4[tid] = make_float4(Wq[(4*cc+0)*32+dd], Wq[(4*cc+1)*32+dd],
                               Wq[(4*cc+2)*32+dd], Wq[(4*cc+3)*32+dd]);
        Wkv4[(2*cc+0)*32+dd] = make_float4(Wk[(4*cc+0)*32+dd], Wv[(4*cc+0)*32+dd],
                                           Wk[(4*cc+1)*32+dd], Wv[(4*cc+1)*32+dd]);
        Wkv4[(2*cc+1)*32+dd] = make_float4(Wk[(4*cc+2)*32+dd], Wv[(4*cc+2)*32+dd],
                                           Wk[(4*cc+3)*32+dd], Wv[(4*cc+3)*32+dd]);
        Wo4[tid] = make_float4(oW[(4*cc+0)*32+dd], oW[(4*cc+1)*32+dd],
                               oW[(4*cc+2)*32+dd], oW[(4*cc+3)*32+dd]);
        if (tid < 4) ab1b[tid] = ab1[tid];
        if (tid < 32) {
            pw2t[tid] = make_float4(pW2[0*32+tid], pW2[1*32+tid], pW2[2*32+tid], pW2[3*32+tid]);
            pb2b[tid] = pb2[tid];
            aw2t[tid] = make_float4(aW2[0*32+tid], aW2[1*32+tid], aW2[2*32+tid], aW2[3*32+tid]);
            ab2b[tid] = ab2[tid];
            obb[tid]  = ob[tid];
            int h = tid & 3, c = tid >> 2;
            aw1col[tid] = make_float4(aW1[(4*c+0)*4+h], aW1[(4*c+1)*4+h],
                                      aW1[(4*c+2)*4+h], aW1[(4*c+3)*4+h]);
        }
    }

    #pragma unroll 1
    for (int t = 0; t < TILES; ++t) {
        const long long tb = (long long)blockIdx.x * TILES + t;
        const long long G0 = tb * NG + gb;

        if (t > 0) __syncthreads();   // prior tile's kb4/qb4/posb/mb readers done

        // ---------------- per-tile staging ----------------
        {
            const float4* kg4 = (const float4*)k;
            const long long kbase = tb * (NG * NSRC * 8);
            #pragma unroll
            for (int r = 0; r < 3; ++r) {
                int i = tid + r * 256;
                if (i < NG * NSRC * 8) kb4[i] = kg4[kbase + i];
            }
            if (tid < NG * 8)
                qb4[tid] = ((const float4*)q)[tb * NG * 8 + tid];
            if (tid < NG * NSRC) {
                // compute pos-MLP hidden ONCE here (was 32x-redundant per lane)
                float4 p4 = ((const float4*)pos)[tb * NG * NSRC + tid];
                float t0 = fmaxf(pb1[0] + p4.x*pW1[0*4+0] + p4.y*pW1[1*4+0] + p4.z*pW1[2*4+0] + p4.w*pW1[3*4+0], 0.f);
                float t1 = fmaxf(pb1[1] + p4.x*pW1[0*4+1] + p4.y*pW1[1*4+1] + p4.z*pW1[2*4+1] + p4.w*pW1[3*4+1], 0.f);
                float t2 = fmaxf(pb1[2] + p4.x*pW1[0*4+2] + p4.y*pW1[1*4+2] + p4.z*pW1[2*4+2] + p4.w*pW1[3*4+2], 0.f);
                float t3 = fmaxf(pb1[3] + p4.x*pW1[0*4+3] + p4.y*pW1[1*4+3] + p4.z*pW1[2*4+3] + p4.w*pW1[3*4+3], 0.f);
                posb[tid] = make_float4(t0, t1, t2, t3);
                mb[tid]   = mask[tb * NG * NSRC + tid];
            }
        }
        __syncthreads();

        // ---------------- pe from precomputed hidden ----------------
        float pe[NSRC];
        {
            const float4 pw2d = pw2t[d]; const float pb2d = pb2b[d];
            #pragma unroll
            for (int n = 0; n < NSRC; ++n) {
                float4 h4 = posb[gb*NSRC + n];
                pe[n] = pb2d + h4.x*pw2d.x + h4.y*pw2d.y + h4.z*pw2d.z + h4.w*pw2d.w;
            }
        }

        // ---------------- mask bits ----------------
        unsigned vbits = 0; int cnt = 0;
        #pragma unroll
        for (int n = 0; n < NSRC; ++n) {
            int m = mb[gb*NSRC + n];
            vbits |= (unsigned)(m != 0) << n;
            cnt += (m != 0);
        }
        if (cnt == 0) { vbits = (1u << NSRC) - 1u; cnt = NSRC; }

        // ---------------- Phase A: q/k/v projections (packed k|v fma) ----------------
        float qp = 0.f;
        floatx2 kpv[NSRC];   // .x = kp, .y = vp  -> v_pk_fma_f32 candidates
        #pragma unroll
        for (int n = 0; n < NSRC; ++n) kpv[n] = floatx2{0.f, 0.f};

        #pragma unroll 2
        for (int c = 0; c < 8; ++c) {
            float4 wq = Wq4[c*32 + d];
            float4 wa = Wkv4[(2*c+0)*32 + d];  // (wk0,wv0,wk1,wv1)
            float4 wb = Wkv4[(2*c+1)*32 + d];  // (wk2,wv2,wk3,wv3)
            float4 q4 = qb4[gb*8 + c];
            qp += q4.x*wq.x + q4.y*wq.y + q4.z*wq.z + q4.w*wq.w;
            #pragma unroll
            for (int n = 0; n < NSRC; ++n) {
                float4 kk = kb4[(gb*NSRC+n)*8 + c];
                kpv[n] = __builtin_elementwise_fma(floatx2{kk.x, kk.x}, floatx2{wa.x, wa.y}, kpv[n]);
                kpv[n] = __builtin_elementwise_fma(floatx2{kk.y, kk.y}, floatx2{wa.z, wa.w}, kpv[n]);
                kpv[n] = __builtin_elementwise_fma(floatx2{kk.z, kk.z}, floatx2{wb.x, wb.y}, kpv[n]);
                kpv[n] = __builtin_elementwise_fma(floatx2{kk.w, kk.w}, floatx2{wb.z, wb.w}, kpv[n]);
            }
        }

        // ---------------- k statistics (store results NOW) ----------------
        {
            const float cntf = (float)cnt;
            const float rc = 1.f / cntf;
            float mean = 0.f, mabs = 0.f;
            #pragma unroll
            for (int n = 0; n < NSRC; ++n) {
                float w = (float)((vbits >> n) & 1u);
                mean += w * kpv[n].x; mabs += w * fabsf(kpv[n].x);
            }
            mean *= rc; mabs *= rc;
            float var = 0.f;
            #pragma unroll
            for (int n = 0; n < NSRC; ++n) {
                float w = (float)((vbits >> n) & 1u);
                float dd2 = kpv[n].x - mean; var += w * dd2 * dd2;
            }
            var *= 1.f / fmaxf(cntf - 1.f, 1.f);
            const float stdv = (cnt == 1) ? 0.f : sqrtf(var);
            const float nksv = (cnt == 1) ? 0.f : stdv / (mabs + 1e-6f);
            out_std[G0*DIM + d] = stdv;
            out_nks[G0*DIM + d] = nksv;
        }

        // fold pe into v-part; pe stays live only through score write
        #pragma unroll
        for (int n = 0; n < NSRC; ++n) kpv[n].y += pe[n];

        // ---------------- scores -> LDS (swizzled); kp/qp/pe die here ----------------
        float* scb = (float*)kb4;
        #pragma unroll
        for (int n = 0; n < NSRC; ++n) {
            int idx = (((d >> 2) ^ (n & 7)) << 2) | (d & 3);
            scb[(gb*NSRC + n)*DIM + idx] = kpv[n].x - qp + pe[n];
        }

        // ---------------- score MLP hidden (cross-lane via LDS) ----------------
        {
            const float4* scb4 = (const float4*)kb4;
            float* ub = (float*)ub4;
            int n = d >> 2, h = d & 3;
            float u = ab1b[h];
            #pragma unroll
            for (int c = 0; c < 8; ++c) {
                float4 s4 = scb4[(gb*NSRC + n)*8 + (c ^ (n & 7))];
                float4 a4 = aw1col[c*4 + h];
                u += s4.x*a4.x + s4.y*a4.y + s4.z*a4.z + s4.w*a4.w;
            }
            ub[gb*NSRC*4 + n*4 + h] = fmaxf(u, 0.f);
            if (d < 8) {
                int n2 = 8 + (d >> 2);
                float u2 = ab1b[h];
                #pragma unroll
                for (int c = 0; c < 8; ++c) {
                    float4 s4 = scb4[(gb*NSRC + n2)*8 + (c ^ (n2 & 7))];
                    float4 a4 = aw1col[c*4 + h];
                    u2 += s4.x*a4.x + s4.y*a4.y + s4.z*a4.z + s4.w*a4.w;
                }
                ub[gb*NSRC*4 + n2*4 + h] = fmaxf(u2, 0.f);
            }
        }

        // ---------------- scores + masked softmax over n ----------------
        float at[NSRC];
        {
            const float4 aw2d = aw2t[d]; const float ab2d = ab2b[d];
            #pragma unroll
            for (int n = 0; n < NSRC; ++n) {
                float4 r4 = ub4[gb*NSRC + n];
                float s = ab2d + r4.x*aw2d.x + r4.y*aw2d.y + r4.z*aw2d.z + r4.w*aw2d.w;
                at[n] = ((vbits >> n) & 1u) ? s : -INFINITY;
            }
        }
        float mx = at[0];
        #pragma unroll
        for (int n = 1; n < NSRC; ++n) mx = fmaxf(mx, at[n]);
        float ssum = 0.f;
        #pragma unroll
        for (int n = 0; n < NSRC; ++n) { float e = __expf(at[n]-mx); at[n] = e; ssum += e; }
        const float rs = 1.f / ssum;

        // ---------------- attn store + output projection ----------------
        // y lives in ub4's gb-region (dead now; all accesses same half-wave -> ordered)
        float y = 0.f;
        {
            const long long abase = G0*(NSRC*DIM) + d;
            #pragma unroll
            for (int n = 0; n < NSRC; ++n) {
                float a = at[n] * rs;
                y += kpv[n].y * a;      // kpv.y == vp+pe
                out_attn[abase + n*DIM] = a;
            }
        }
        float* ybg = (float*)(ub4 + gb*NSRC);   // 160B region >= 128B needed
        ybg[d] = y;
        {
            const float4* ybg4 = (const float4*)ybg;
            float x = obb[d];
            #pragma unroll
            for (int c = 0; c < 8; ++c) {
                float4 wo = Wo4[c*32 + d];
                float4 y4 = ybg4[c];
                x += y4.x*wo.x + y4.y*wo.y + y4.z*wo.z + y4.w*wo.w;
            }
            out_x[G0*DIM + d] = x;
        }
    }
}

extern "C" void kernel_launch(void* const* d_in, const int* in_sizes, int n_in,
                              void* d_out, int out_size, void* d_ws, size_t ws_size,
                              hipStream_t stream) {
    const float* q    = (const float*)d_in[0];
    const float* k    = (const float*)d_in[1];
    const float* pos  = (const float*)d_in[2];
    const int*   mask = (const int*)  d_in[3];
    const float* Wq   = (const float*)d_in[4];
    const float* Wk   = (const float*)d_in[5];
    const float* Wv   = (const float*)d_in[6];
    const float* pW1  = (const float*)d_in[7];
    const float* pb1  = (const float*)d_in[8];
    const float* pW2  = (const float*)d_in[9];
    const float* pb2  = (const float*)d_in[10];
    const float* aW1  = (const float*)d_in[11];
    const float* ab1  = (const float*)d_in[12];
    const float* aW2  = (const float*)d_in[13];
    const float* ab2  = (const float*)d_in[14];
    const float* oW   = (const float*)d_in[15];
    const float* ob   = (const float*)d_in[16];

    const int G = in_sizes[0] / DIM;            // R*S = 131072 groups
    const int blocks = G / (NG * TILES);        // 4096 persistent blocks

    float* out_x    = (float*)d_out;
    float* out_attn = out_x + (long long)G * DIM;
    float* out_std  = out_attn + (long long)G * NSRC * DIM;
    float* out_nks  = out_std + (long long)G * DIM;

    attn2d_kernel<<<blocks, 256, 0, stream>>>(
        q, k, pos, mask, Wq, Wk, Wv, pW1, pb1, pW2, pb2,
        aW1, ab1, aW2, ab2, oW, ob,
        out_x, out_attn, out_std, out_nks);
}